// Round 6
// baseline (1339.606 us; speedup 1.0000x reference)
//
#include <hip/hip_runtime.h>
#include <stdint.h>
#include <stddef.h>

typedef __bf16 bf16_t;
typedef __bf16 bf16x4 __attribute__((ext_vector_type(4)));
typedef __bf16 bf16x8 __attribute__((ext_vector_type(8)));
typedef float  f32x4  __attribute__((ext_vector_type(4)));

#define H_   12
#define N_   49
#define C_   384
#define D_   32
#define NW_  64
#define C3_  1152

// ---- LDS layout (bytes) ----
// region 0: xs (49 x 392 bf16) — x[it] for P2; P-overlay (12x2304B) in P3;
//           rewritten with x[it+1] during P4 (after B2), published at B3.
// region 1: qa (49 x 392 bf16) — q [tok][dim] in P3, ao in P4
// region 2: ka (49 x 392 bf16) — k [tok][dim]
// region 3: vt (384 x 56 bf16, [dim][tok]) + 32B read guard
#define XS_STRIDE 392
#define Q_OFF     38416
#define K_OFF     76832
#define VT_OFF    115248
#define VT_STRIDE 56
#define P_STRIDE  72            // elems; per-wave P: 16 rows x 144B = 2304 B
#define SMEM_BYTES 158288       // 115248 + 384*112 + 32 guard

#define WQKV_ELEMS  (C3_ * C_)   // 442368
#define WPROJ_ELEMS (C_ * C_)    // 147456

#define NBLK  256
#define NITER 8                  // 2048 windows / 256 blocks

// ---------------------------------------------------------------------------
// prep_all: merged weight transpose + bias table build (one launch).
// blocks 0..287: frag-order transpose of qkv_w/proj_w.
// blocks 288..1055: btbl[w][h][m][n] = (rpb+mask)*log2e, n padded to 64.
// ---------------------------------------------------------------------------
__global__ void prep_all(const float* __restrict__ qkv_w,
                         const float* __restrict__ proj_w,
                         const float* __restrict__ mask,
                         const float* __restrict__ rpb,
                         bf16_t* __restrict__ wqkvT,
                         bf16_t* __restrict__ wprojT,
                         bf16_t* __restrict__ btbl)
{
    __shared__ bf16_t tile[32][72];
    int bid = blockIdx.x;
    const int t = threadIdx.x;
    if (bid < 288) {
        const float* src; bf16_t* dst; int NC, ks, g;
        if (bid < 216) { src = qkv_w;  dst = wqkvT;  NC = C3_; ks = bid % 12; g = bid / 12; }
        else { bid -= 216; src = proj_w; dst = wprojT; NC = C_;  ks = bid % 12; g = bid / 12; }
        const int n0 = g * 64;
        const int r0 = t >> 6, cc = t & 63;
        #pragma unroll
        for (int p = 0; p < 8; ++p) {
            int row = p * 4 + r0;
            tile[row][cc] = (bf16_t)src[(ks * 32 + row) * NC + n0 + cc];
        }
        __syncthreads();
        const int lane = t & 63, ctl = t >> 6;
        const int q4 = lane >> 4, l15 = lane & 15;
        bf16x8 v;
        #pragma unroll
        for (int j = 0; j < 8; ++j) v[j] = tile[q4 * 8 + j][ctl * 16 + l15];
        *(bf16x8*)(dst + ((size_t)((g * 4 + ctl) * 12 + ks) * 64 + lane) * 8) = v;
    } else {
        bid -= 288;
        const int w = bid / H_, h = bid % H_;
        bf16_t* out = btbl + (size_t)(w * H_ + h) * (N_ * 64);
        for (int idx = t; idx < N_ * 64; idx += 256) {
            int m = idx >> 6, n = idx & 63;
            float v = 0.f;
            if (n < N_)
                v = (rpb[(h * N_ + m) * N_ + n] + mask[((size_t)w * N_ + m) * N_ + n])
                    * 1.4426950408889634f;
            out[idx] = (bf16_t)v;
        }
    }
}

// ---------------------------------------------------------------------------
// Persistent fused kernel: 256 blocks (1/CU), 12 waves, 8 windows/block
// (w = b + 256*it; w&63 == b&63 so the btbl slice stays L2-hot).
// Loop: P2 | B1 | P3 | B2 | P4 (+x[it+1] reg-prefetch under MFMA, xs
// rewrite at end) | B3.  Prefetch registers cross ZERO barriers (round-3
// spill lesson); phase-1's per-block cold-load stall is eliminated.
// ---------------------------------------------------------------------------
__global__ __launch_bounds__(768, 3)
void fused_window_attn(const float* __restrict__ x,
                       const float* __restrict__ qkv_b,
                       const float* __restrict__ proj_b,
                       const bf16_t* __restrict__ wqkvT,
                       const bf16_t* __restrict__ wprojT,
                       const bf16_t* __restrict__ btbl,
                       float* __restrict__ out)
{
    __shared__ __align__(16) unsigned char smem[SMEM_BYTES];
    bf16_t* xs = (bf16_t*)smem;                 // x tile; P-overlay in P3
    bf16_t* qa = (bf16_t*)(smem + Q_OFF);       // q [tok][dim], later ao
    bf16_t* ka = (bf16_t*)(smem + K_OFF);       // k [tok][dim]
    bf16_t* vt = (bf16_t*)(smem + VT_OFF);      // v^T [dim][tok]

    const int tid  = threadIdx.x;
    const int wave = tid >> 6;                  // 0..11
    const int lane = tid & 63;
    const int q4   = lane >> 4;
    const int l15  = lane & 15;
    const int b    = blockIdx.x;                // 0..255

    const f32x4 z4 = {0.f, 0.f, 0.f, 0.f};
    const float SC = 0.17677669529663687f * 1.4426950408889634f;
    const bf16_t* tb = btbl + (size_t)((b & (NW_ - 1)) * H_ + wave) * (N_ * 64);

    // ---------------- prologue: vt pad zero (once) + x[b] -> xs -----------
    {
        // Zero vt token-columns 48..55 of every row + the 32B tail guard.
        // Tokens 49..55 are never written by P2's epilogue B but ARE read
        // (x P==0) by the PV b128 fragments: 0*NaN = NaN -> need real zeros.
        // Epilogue B never writes cols >= 49, so one-time zeroing persists.
        for (int t = tid; t < 384 * 8; t += 768) {
            int r = t >> 3, c = t & 7;
            vt[r * VT_STRIDE + 48 + c] = (bf16_t)0.f;
        }
        if (tid < 16) vt[384 * VT_STRIDE + tid] = (bf16_t)0.f;

        const float* xg = x + (size_t)b * (N_ * C_);
        for (int t = tid; t < (N_ * C_) / 4; t += 768) {
            float4 v = ((const float4*)xg)[t];
            int r = t / 96, c4 = t % 96;
            bf16x4 o;
            o[0] = (bf16_t)v.x; o[1] = (bf16_t)v.y;
            o[2] = (bf16_t)v.z; o[3] = (bf16_t)v.w;
            *(bf16x4*)(xs + r * XS_STRIDE + c4 * 4) = o;
        }
    }
    __syncthreads();

    #pragma unroll 1
    for (int it = 0; it < NITER; ++it) {
        const int w = b + NBLK * it;

        // ------------- phase 2: qkv GEMM, 2 passes x 3 tiles per wave -----
        // waves 0..7:  A-type (swapped), q+k cols; waves 8..11: B-type, v.
        if (wave < 8) {
            #pragma unroll
            for (int p = 0; p < 2; ++p) {
                const int tb0 = wave * 6 + p * 3;
                f32x4 acc[3][4];
                #pragma unroll
                for (int jj = 0; jj < 3; ++jj)
                    #pragma unroll
                    for (int mi = 0; mi < 4; ++mi) acc[jj][mi] = z4;

                bf16x8 wfc[3], xfc[4];
                #pragma unroll
                for (int jj = 0; jj < 3; ++jj)
                    wfc[jj] = *(const bf16x8*)(wqkvT +
                        ((size_t)((tb0 + jj) * 12 + 0) * 64 + lane) * 8);
                #pragma unroll
                for (int mi = 0; mi < 4; ++mi)
                    xfc[mi] = *(const bf16x8*)(xs + (mi * 16 + l15) * XS_STRIDE + q4 * 8);

                #pragma unroll
                for (int ks = 0; ks < 12; ++ks) {
                    bf16x8 wfn[3], xfn[4];
                    if (ks < 11) {
                        #pragma unroll
                        for (int jj = 0; jj < 3; ++jj)
                            wfn[jj] = *(const bf16x8*)(wqkvT +
                                ((size_t)((tb0 + jj) * 12 + ks + 1) * 64 + lane) * 8);
                        #pragma unroll
                        for (int mi = 0; mi < 4; ++mi)
                            xfn[mi] = *(const bf16x8*)(xs + (mi * 16 + l15) * XS_STRIDE
                                                          + (ks + 1) * 32 + q4 * 8);
                    }
                    #pragma unroll
                    for (int jj = 0; jj < 3; ++jj)
                        #pragma unroll
                        for (int mi = 0; mi < 4; ++mi)
                            acc[jj][mi] = __builtin_amdgcn_mfma_f32_16x16x32_bf16(
                                wfc[jj], xfc[mi], acc[jj][mi], 0, 0, 0);
                    if (ks < 11) {
                        #pragma unroll
                        for (int jj = 0; jj < 3; ++jj) wfc[jj] = wfn[jj];
                        #pragma unroll
                        for (int mi = 0; mi < 4; ++mi) xfc[mi] = xfn[mi];
                    }
                }
                // epilogue A: (chan=ct*16+q4*4+r, tok=l15) -> q/k [tok][chan]
                #pragma unroll
                for (int jj = 0; jj < 3; ++jj) {
                    const int ct = tb0 + jj;
                    const int c0 = ct * 16 + q4 * 4;
                    float4 bv = *(const float4*)(qkv_b + c0);
                    bf16_t* dst = (ct < 24) ? qa : ka;
                    const int cc = c0 - (ct < 24 ? 0 : C_);
                    #pragma unroll
                    for (int mi = 0; mi < 4; ++mi) {
                        const int m = mi * 16 + l15;
                        if (m < N_) {
                            bf16x4 o;
                            o[0] = (bf16_t)(acc[jj][mi][0] + bv.x);
                            o[1] = (bf16_t)(acc[jj][mi][1] + bv.y);
                            o[2] = (bf16_t)(acc[jj][mi][2] + bv.z);
                            o[3] = (bf16_t)(acc[jj][mi][3] + bv.w);
                            *(bf16x4*)(dst + m * XS_STRIDE + cc) = o;
                        }
                    }
                }
            }
        } else {
            #pragma unroll
            for (int p = 0; p < 2; ++p) {
                const int tb0 = 48 + (wave - 8) * 6 + p * 3;
                f32x4 acc[3][4];
                #pragma unroll
                for (int jj = 0; jj < 3; ++jj)
                    #pragma unroll
                    for (int mi = 0; mi < 4; ++mi) acc[jj][mi] = z4;

                bf16x8 wfc[3], xfc[4];
                #pragma unroll
                for (int jj = 0; jj < 3; ++jj)
                    wfc[jj] = *(const bf16x8*)(wqkvT +
                        ((size_t)((tb0 + jj) * 12 + 0) * 64 + lane) * 8);
                #pragma unroll
                for (int mi = 0; mi < 4; ++mi)
                    xfc[mi] = *(const bf16x8*)(xs + (mi * 16 + l15) * XS_STRIDE + q4 * 8);

                #pragma unroll
                for (int ks = 0; ks < 12; ++ks) {
                    bf16x8 wfn[3], xfn[4];
                    if (ks < 11) {
                        #pragma unroll
                        for (int jj = 0; jj < 3; ++jj)
                            wfn[jj] = *(const bf16x8*)(wqkvT +
                                ((size_t)((tb0 + jj) * 12 + ks + 1) * 64 + lane) * 8);
                        #pragma unroll
                        for (int mi = 0; mi < 4; ++mi)
                            xfn[mi] = *(const bf16x8*)(xs + (mi * 16 + l15) * XS_STRIDE
                                                          + (ks + 1) * 32 + q4 * 8);
                    }
                    #pragma unroll
                    for (int jj = 0; jj < 3; ++jj)
                        #pragma unroll
                        for (int mi = 0; mi < 4; ++mi)
                            acc[jj][mi] = __builtin_amdgcn_mfma_f32_16x16x32_bf16(
                                xfc[mi], wfc[jj], acc[jj][mi], 0, 0, 0);
                    if (ks < 11) {
                        #pragma unroll
                        for (int jj = 0; jj < 3; ++jj) wfc[jj] = wfn[jj];
                        #pragma unroll
                        for (int mi = 0; mi < 4; ++mi) xfc[mi] = xfn[mi];
                    }
                }
                // epilogue B: (tok=q4*4+r+mi*16, chan=ct*16+l15) -> vT
                #pragma unroll
                for (int jj = 0; jj < 3; ++jj) {
                    const int ct = tb0 + jj;         // 48..71
                    const int c  = ct * 16 + l15;
                    const int d  = c - 2 * C_;       // v dim 0..383
                    const float bb = qkv_b[c];
                    #pragma unroll
                    for (int mi = 0; mi < 4; ++mi) {
                        const int t0 = mi * 16 + q4 * 4;
                        if (t0 + 3 < N_) {
                            bf16x4 o;
                            #pragma unroll
                            for (int r = 0; r < 4; ++r) o[r] = (bf16_t)(acc[jj][mi][r] + bb);
                            *(bf16x4*)(vt + d * VT_STRIDE + t0) = o;
                        } else {
                            #pragma unroll
                            for (int r = 0; r < 4; ++r)
                                if (t0 + r < N_)
                                    vt[d * VT_STRIDE + t0 + r] = (bf16_t)(acc[jj][mi][r] + bb);
                        }
                    }
                }
            }
        }
        __syncthreads();   // B1: q/k/vt ready; xs (x[it]) now dead

        // ------------- phase 3: attention, wave = head, 4 row-tiles -------
        // ao staged inline: wave h touches only qa cols [h*32,h*32+32);
        // rows written for tile mt are never re-read by later qf loads.
        {
            bf16_t* pb = (bf16_t*)(smem + wave * 2304);   // P-overlay in xs
            bf16x8 kf[4];
            #pragma unroll
            for (int ni = 0; ni < 4; ++ni)
                kf[ni] = *(const bf16x8*)(ka + (ni * 16 + l15) * XS_STRIDE
                                             + wave * D_ + q4 * 8);
            bf16x8 vf[2][2];
            #pragma unroll
            for (int ks2 = 0; ks2 < 2; ++ks2)
                #pragma unroll
                for (int dt = 0; dt < 2; ++dt)
                    vf[ks2][dt] = *(const bf16x8*)(vt + (wave * D_ + dt * 16 + l15) * VT_STRIDE
                                                      + ks2 * 32 + q4 * 8);

            #pragma unroll
            for (int mt = 0; mt < 4; ++mt) {
                bf16x8 qf = *(const bf16x8*)(qa + (mt * 16 + l15) * XS_STRIDE
                                                + wave * D_ + q4 * 8);
                // S^T[n][m]
                f32x4 sacc[4];
                #pragma unroll
                for (int ni = 0; ni < 4; ++ni)
                    sacc[ni] = __builtin_amdgcn_mfma_f32_16x16x32_bf16(
                        kf[ni], qf, z4, 0, 0, 0);

                // bias + exp2 + row sum (lane's m = mt*16+l15)
                const int m  = mt * 16 + l15;
                const int mc = m < 48 ? m : 48;
                float den = 0.f;
                #pragma unroll
                for (int ni = 0; ni < 4; ++ni) {
                    bf16x4 bv = *(const bf16x4*)(tb + (size_t)mc * 64 + ni * 16 + q4 * 4);
                    #pragma unroll
                    for (int r = 0; r < 4; ++r) {
                        const int n = ni * 16 + q4 * 4 + r;
                        float s = 0.f;
                        if (n < N_)
                            s = __builtin_exp2f(sacc[ni][r] * SC + (float)bv[r]);
                        sacc[ni][r] = s;
                        den += s;
                    }
                }
                den += __shfl_xor(den, 16);
                den += __shfl_xor(den, 32);
                const float ri = __builtin_amdgcn_rcpf(den);

                // P write (exact zeros for n>=49; rows m>=49 skipped)
                if (m < N_) {
                    #pragma unroll
                    for (int ni = 0; ni < 4; ++ni) {
                        bf16x4 o;
                        #pragma unroll
                        for (int r = 0; r < 4; ++r) o[r] = (bf16_t)(sacc[ni][r] * ri);
                        *(bf16x4*)(pb + l15 * P_STRIDE + ni * 16 + q4 * 4) = o;
                    }
                }

                // out = P @ V ; stage ao inline
                f32x4 o0 = z4, o1 = z4;
                #pragma unroll
                for (int ks2 = 0; ks2 < 2; ++ks2) {
                    bf16x8 pf = *(const bf16x8*)(pb + l15 * P_STRIDE + ks2 * 32 + q4 * 8);
                    o0 = __builtin_amdgcn_mfma_f32_16x16x32_bf16(pf, vf[ks2][0], o0, 0, 0, 0);
                    o1 = __builtin_amdgcn_mfma_f32_16x16x32_bf16(pf, vf[ks2][1], o1, 0, 0, 0);
                }
                #pragma unroll
                for (int r = 0; r < 4; ++r) {
                    const int ms = mt * 16 + q4 * 4 + r;
                    if (ms < N_) {
                        qa[ms * XS_STRIDE + wave * D_ + l15]      = (bf16_t)o0[r];
                        qa[ms * XS_STRIDE + wave * D_ + 16 + l15] = (bf16_t)o1[r];
                    }
                }
            }
        }
        __syncthreads();   // B2: ao complete; P-overlay dead; xs writable

        // ------------- phase 4: out = ao @ Wproj + b; x[it+1] prefetch ----
        {
            // issue next-window x loads FIRST: HBM latency hides under the
            // 96 MFMAs below. Registers live only within this phase.
            float4 x0, x1, x2, x3, x4, x5, x6;
            const bool pf_x = (it < NITER - 1);
            if (pf_x) {
                const float4* nxg = (const float4*)(x + (size_t)(w + NBLK) * (N_ * C_));
                x0 = nxg[tid];
                x1 = nxg[tid + 768];
                x2 = nxg[tid + 1536];
                x3 = nxg[tid + 2304];
                x4 = nxg[tid + 3072];
                x5 = nxg[tid + 3840];
                if (tid < 96) x6 = nxg[tid + 4608];
            }

            f32x4 pacc[2][4];
            #pragma unroll
            for (int jj = 0; jj < 2; ++jj)
                #pragma unroll
                for (int mi = 0; mi < 4; ++mi) pacc[jj][mi] = z4;

            bf16x8 wfc[2], afc[4];
            #pragma unroll
            for (int jj = 0; jj < 2; ++jj)
                wfc[jj] = *(const bf16x8*)(wprojT +
                    ((size_t)((wave * 2 + jj) * 12 + 0) * 64 + lane) * 8);
            #pragma unroll
            for (int mi = 0; mi < 4; ++mi)
                afc[mi] = *(const bf16x8*)(qa + (mi * 16 + l15) * XS_STRIDE + q4 * 8);

            #pragma unroll
            for (int ks = 0; ks < 12; ++ks) {
                bf16x8 wfn[2], afn[4];
                if (ks < 11) {
                    #pragma unroll
                    for (int jj = 0; jj < 2; ++jj)
                        wfn[jj] = *(const bf16x8*)(wprojT +
                            ((size_t)((wave * 2 + jj) * 12 + ks + 1) * 64 + lane) * 8);
                    #pragma unroll
                    for (int mi = 0; mi < 4; ++mi)
                        afn[mi] = *(const bf16x8*)(qa + (mi * 16 + l15) * XS_STRIDE
                                                      + (ks + 1) * 32 + q4 * 8);
                }
                #pragma unroll
                for (int jj = 0; jj < 2; ++jj)
                    #pragma unroll
                    for (int mi = 0; mi < 4; ++mi)
                        pacc[jj][mi] = __builtin_amdgcn_mfma_f32_16x16x32_bf16(
                            afc[mi], wfc[jj], pacc[jj][mi], 0, 0, 0);
                if (ks < 11) {
                    #pragma unroll
                    for (int jj = 0; jj < 2; ++jj) wfc[jj] = wfn[jj];
                    #pragma unroll
                    for (int mi = 0; mi < 4; ++mi) afc[mi] = afn[mi];
                }
            }
            float* og = out + (size_t)w * (N_ * C_);
            #pragma unroll
            for (int jj = 0; jj < 2; ++jj) {
                const int n = (wave * 2 + jj) * 16 + l15;
                const float bias = proj_b[n];
                #pragma unroll
                for (int mi = 0; mi < 4; ++mi) {
                    #pragma unroll
                    for (int r = 0; r < 4; ++r) {
                        const int m = mi * 16 + q4 * 4 + r;
                        if (m < N_) og[m * C_ + n] = pacc[jj][mi][r] + bias;
                    }
                }
            }

            // late: convert + publish x[it+1] into xs (dead since B1; the
            // P-overlay region is dead since B2). Published at B3 below.
            if (pf_x) {
                const float4 xr[6] = {x0, x1, x2, x3, x4, x5};
                #pragma unroll
                for (int kk = 0; kk < 6; ++kk) {
                    int t = tid + 768 * kk;
                    int r = t / 96, c4 = t % 96;
                    bf16x4 o;
                    o[0] = (bf16_t)xr[kk].x; o[1] = (bf16_t)xr[kk].y;
                    o[2] = (bf16_t)xr[kk].z; o[3] = (bf16_t)xr[kk].w;
                    *(bf16x4*)(xs + r * XS_STRIDE + c4 * 4) = o;
                }
                if (tid < 96) {
                    bf16x4 o;
                    o[0] = (bf16_t)x6.x; o[1] = (bf16_t)x6.y;
                    o[2] = (bf16_t)x6.z; o[3] = (bf16_t)x6.w;
                    *(bf16x4*)(xs + 48 * XS_STRIDE + tid * 4) = o;
                }
            }
        }
        __syncthreads();   // B3: out written, xs[it+1] published
    }
}

// ---------------------------------------------------------------------------
extern "C" void kernel_launch(void* const* d_in, const int* in_sizes, int n_in,
                              void* d_out, int out_size, void* d_ws, size_t ws_size,
                              hipStream_t stream)
{
    const float* x      = (const float*)d_in[0];
    const float* mask   = (const float*)d_in[1];
    const float* qkv_w  = (const float*)d_in[2];
    const float* qkv_b  = (const float*)d_in[3];
    const float* proj_w = (const float*)d_in[4];
    const float* proj_b = (const float*)d_in[5];
    const float* rpb    = (const float*)d_in[6];
    float* out = (float*)d_out;

    bf16_t* wqkvT  = (bf16_t*)d_ws;
    bf16_t* wprojT = wqkvT + WQKV_ELEMS;
    bf16_t* btbl   = wprojT + WPROJ_ELEMS;   // 64*12*49*64 bf16 = 4.8 MB

    prep_all<<<288 + NW_ * H_, 256, 0, stream>>>(qkv_w, proj_w, mask, rpb,
                                                 wqkvT, wprojT, btbl);
    fused_window_attn<<<NBLK, 768, 0, stream>>>(x, qkv_b, proj_b,
                                                wqkvT, wprojT, btbl, out);
}

// Round 7
// 472.679 us; speedup vs baseline: 2.8341x; 2.8341x over previous
//
#include <hip/hip_runtime.h>
#include <stdint.h>
#include <stddef.h>

typedef __bf16 bf16_t;
typedef __bf16 bf16x4 __attribute__((ext_vector_type(4)));
typedef __bf16 bf16x8 __attribute__((ext_vector_type(8)));
typedef float  f32x4  __attribute__((ext_vector_type(4)));

#define H_   12
#define N_   49
#define C_   384
#define D_   32
#define NW_  64
#define C3_  1152

// ---- LDS layout (bytes) ----
// region 0: xs (phase1/2: 49 x 392 bf16) / per-wave P buffers (phase 3)
// region 1: qa (49 x 392 bf16) — q [tok][dim] in P3, ao in P4
// region 2: ka (49 x 392 bf16) — k [tok][dim]
// region 3: vt (384 x 56 bf16, [dim][tok]) + 32B read guard
#define XS_STRIDE 392
#define Q_OFF     38416
#define K_OFF     76832
#define VT_OFF    115248
#define VT_STRIDE 56
#define P_STRIDE  72            // elems; per-wave P: 16 rows x 144B = 2304 B
#define SMEM_BYTES 158288       // 115248 + 384*112 + 32 guard

#define WQKV_ELEMS  (C3_ * C_)   // 442368
#define WPROJ_ELEMS (C_ * C_)    // 147456

// ---------------------------------------------------------------------------
// prep_all: merged weight transpose + bias table build (one launch).
// blocks 0..287: frag-order transpose of qkv_w/proj_w.
// blocks 288..1055: btbl[w][h][m][n] = (rpb+mask)*log2e, n padded to 64.
// ---------------------------------------------------------------------------
__global__ void prep_all(const float* __restrict__ qkv_w,
                         const float* __restrict__ proj_w,
                         const float* __restrict__ mask,
                         const float* __restrict__ rpb,
                         bf16_t* __restrict__ wqkvT,
                         bf16_t* __restrict__ wprojT,
                         bf16_t* __restrict__ btbl)
{
    __shared__ bf16_t tile[32][72];
    int bid = blockIdx.x;
    const int t = threadIdx.x;
    if (bid < 288) {
        const float* src; bf16_t* dst; int NC, ks, g;
        if (bid < 216) { src = qkv_w;  dst = wqkvT;  NC = C3_; ks = bid % 12; g = bid / 12; }
        else { bid -= 216; src = proj_w; dst = wprojT; NC = C_;  ks = bid % 12; g = bid / 12; }
        const int n0 = g * 64;
        const int r0 = t >> 6, cc = t & 63;
        #pragma unroll
        for (int p = 0; p < 8; ++p) {
            int row = p * 4 + r0;
            tile[row][cc] = (bf16_t)src[(ks * 32 + row) * NC + n0 + cc];
        }
        __syncthreads();
        const int lane = t & 63, ctl = t >> 6;
        const int q4 = lane >> 4, l15 = lane & 15;
        bf16x8 v;
        #pragma unroll
        for (int j = 0; j < 8; ++j) v[j] = tile[q4 * 8 + j][ctl * 16 + l15];
        *(bf16x8*)(dst + ((size_t)((g * 4 + ctl) * 12 + ks) * 64 + lane) * 8) = v;
    } else {
        bid -= 288;
        const int w = bid / H_, h = bid % H_;
        bf16_t* out = btbl + (size_t)(w * H_ + h) * (N_ * 64);
        for (int idx = t; idx < N_ * 64; idx += 256) {
            int m = idx >> 6, n = idx & 63;
            float v = 0.f;
            if (n < N_)
                v = (rpb[(h * N_ + m) * N_ + n] + mask[((size_t)w * N_ + m) * N_ + n])
                    * 1.4426950408889634f;
            out[idx] = (bf16_t)v;
        }
    }
}

// ---------------------------------------------------------------------------
// P3 step macro: fully static, alternating SCUR/SNXT accumulator sets.
// Order per step: [qf(mt+1) LDS load] [softmax(mt) VALU — hides the load]
// [P write(mt)] [QK(mt+1) MFMAs — fill the P write->read round trip]
// [P read + PV(mt)] [ao write(mt)].  setprio(1) around the MFMA clusters.
// ---------------------------------------------------------------------------
#define P3_STEP(MT, SCUR, SNXT, LAST)                                          \
  {                                                                            \
    bf16x8 qfn;                                                                \
    if (!(LAST))                                                               \
        qfn = *(const bf16x8*)(qa + (((MT) + 1) * 16 + l15) * XS_STRIDE        \
                                  + wave * D_ + q4 * 8);                       \
    const int m  = (MT) * 16 + l15;                                            \
    const int mc = m < 48 ? m : 48;                                            \
    float den = 0.f;                                                           \
    _Pragma("unroll")                                                          \
    for (int ni = 0; ni < 4; ++ni) {                                           \
        bf16x4 bv = *(const bf16x4*)(tb + (size_t)mc * 64 + ni * 16 + q4 * 4); \
        _Pragma("unroll")                                                      \
        for (int r = 0; r < 4; ++r) {                                          \
            const int n = ni * 16 + q4 * 4 + r;                                \
            float s = 0.f;                                                     \
            if (n < N_)                                                        \
                s = __builtin_exp2f(SCUR[ni][r] * SC + (float)bv[r]);          \
            SCUR[ni][r] = s;                                                   \
            den += s;                                                          \
        }                                                                      \
    }                                                                          \
    den += __shfl_xor(den, 16);                                                \
    den += __shfl_xor(den, 32);                                                \
    const float ri = __builtin_amdgcn_rcpf(den);                               \
    if (m < N_) {                                                              \
        _Pragma("unroll")                                                      \
        for (int ni = 0; ni < 4; ++ni) {                                       \
            bf16x4 o;                                                          \
            _Pragma("unroll")                                                  \
            for (int r = 0; r < 4; ++r) o[r] = (bf16_t)(SCUR[ni][r] * ri);     \
            *(bf16x4*)(pb + l15 * P_STRIDE + ni * 16 + q4 * 4) = o;            \
        }                                                                      \
    }                                                                          \
    __builtin_amdgcn_s_setprio(1);                                             \
    if (!(LAST)) {                                                             \
        _Pragma("unroll")                                                      \
        for (int ni = 0; ni < 4; ++ni)                                         \
            SNXT[ni] = __builtin_amdgcn_mfma_f32_16x16x32_bf16(                \
                kf[ni], qfn, z4, 0, 0, 0);                                     \
    }                                                                          \
    f32x4 o0 = z4, o1 = z4;                                                    \
    _Pragma("unroll")                                                          \
    for (int ks2 = 0; ks2 < 2; ++ks2) {                                        \
        bf16x8 pf = *(const bf16x8*)(pb + l15 * P_STRIDE + ks2 * 32 + q4 * 8); \
        o0 = __builtin_amdgcn_mfma_f32_16x16x32_bf16(pf, vf[ks2][0], o0, 0, 0, 0); \
        o1 = __builtin_amdgcn_mfma_f32_16x16x32_bf16(pf, vf[ks2][1], o1, 0, 0, 0); \
    }                                                                          \
    __builtin_amdgcn_s_setprio(0);                                             \
    _Pragma("unroll")                                                          \
    for (int r = 0; r < 4; ++r) {                                              \
        const int ms = (MT) * 16 + q4 * 4 + r;                                 \
        if (ms < N_) {                                                         \
            qa[ms * XS_STRIDE + wave * D_ + l15]      = (bf16_t)o0[r];         \
            qa[ms * XS_STRIDE + wave * D_ + 16 + l15] = (bf16_t)o1[r];         \
        }                                                                      \
    }                                                                          \
  }

// ---------------------------------------------------------------------------
// Fused per-window kernel: one block per window b, 12 waves (768 threads).
//   phase 2: 72 column-tiles -> 6/wave, 2 passes x 3 tiles, 1-ahead prefetch
//   phase 3: wave = head, 4 row-tiles, software-pipelined (QK(mt+1) overlaps
//            softmax(mt) + P LDS round trip); ao staged inline
//   phase 4: 2 column-tiles/wave with 1-ahead prefetch
// ---------------------------------------------------------------------------
__global__ __launch_bounds__(768, 3)
void fused_window_attn(const float* __restrict__ x,
                       const float* __restrict__ qkv_b,
                       const float* __restrict__ proj_b,
                       const bf16_t* __restrict__ wqkvT,
                       const bf16_t* __restrict__ wprojT,
                       const bf16_t* __restrict__ btbl,
                       float* __restrict__ out)
{
    __shared__ __align__(16) unsigned char smem[SMEM_BYTES];
    bf16_t* xs = (bf16_t*)smem;                 // phase 1/2; P buffers in P3
    bf16_t* qa = (bf16_t*)(smem + Q_OFF);       // q [tok][dim], later ao
    bf16_t* ka = (bf16_t*)(smem + K_OFF);       // k [tok][dim]
    bf16_t* vt = (bf16_t*)(smem + VT_OFF);      // v^T [dim][tok]

    const int tid  = threadIdx.x;
    const int wave = tid >> 6;                  // 0..11
    const int lane = tid & 63;
    const int q4   = lane >> 4;
    const int l15  = lane & 15;
    const int b    = blockIdx.x;

    const f32x4 z4 = {0.f, 0.f, 0.f, 0.f};

    // ---------------- phase 1: x[b] -> bf16 LDS; zero vt padding ----------
    {
        // Zero vt token-columns 48..55 of every row + the 32B tail guard.
        // Tokens 49..55 are never written by phase 2 but ARE read (x P==0)
        // by the PV b128 fragments: 0*NaN = NaN, so they must be real zeros.
        for (int t = tid; t < 384 * 8; t += 768) {
            int r = t >> 3, c = t & 7;
            vt[r * VT_STRIDE + 48 + c] = (bf16_t)0.f;
        }
        if (tid < 16) vt[384 * VT_STRIDE + tid] = (bf16_t)0.f;

        const float* xg = x + (size_t)b * (N_ * C_);
        for (int t = tid; t < (N_ * C_) / 4; t += 768) {
            float4 v = ((const float4*)xg)[t];
            int r = t / 96, c4 = t % 96;
            bf16x4 o;
            o[0] = (bf16_t)v.x; o[1] = (bf16_t)v.y;
            o[2] = (bf16_t)v.z; o[3] = (bf16_t)v.w;
            *(bf16x4*)(xs + r * XS_STRIDE + c4 * 4) = o;
        }
    }
    __syncthreads();

    // ---------------- phase 2: qkv GEMM, 2 passes x 3 tiles per wave ------
    // waves 0..7:  A-type (swapped operands), q+k cols, ct = wave*6 .. +5
    // waves 8..11: B-type (normal), v cols, ct = 48 + (wave-8)*6 .. +5
    if (wave < 8) {
        #pragma unroll
        for (int p = 0; p < 2; ++p) {
            const int tb0 = wave * 6 + p * 3;
            f32x4 acc[3][4];
            #pragma unroll
            for (int jj = 0; jj < 3; ++jj)
                #pragma unroll
                for (int mi = 0; mi < 4; ++mi) acc[jj][mi] = z4;

            bf16x8 wfc[3], xfc[4];
            #pragma unroll
            for (int jj = 0; jj < 3; ++jj)
                wfc[jj] = *(const bf16x8*)(wqkvT +
                    ((size_t)((tb0 + jj) * 12 + 0) * 64 + lane) * 8);
            #pragma unroll
            for (int mi = 0; mi < 4; ++mi)
                xfc[mi] = *(const bf16x8*)(xs + (mi * 16 + l15) * XS_STRIDE + q4 * 8);

            #pragma unroll
            for (int ks = 0; ks < 12; ++ks) {
                bf16x8 wfn[3], xfn[4];
                if (ks < 11) {
                    #pragma unroll
                    for (int jj = 0; jj < 3; ++jj)
                        wfn[jj] = *(const bf16x8*)(wqkvT +
                            ((size_t)((tb0 + jj) * 12 + ks + 1) * 64 + lane) * 8);
                    #pragma unroll
                    for (int mi = 0; mi < 4; ++mi)
                        xfn[mi] = *(const bf16x8*)(xs + (mi * 16 + l15) * XS_STRIDE
                                                      + (ks + 1) * 32 + q4 * 8);
                }
                #pragma unroll
                for (int jj = 0; jj < 3; ++jj)
                    #pragma unroll
                    for (int mi = 0; mi < 4; ++mi)
                        acc[jj][mi] = __builtin_amdgcn_mfma_f32_16x16x32_bf16(
                            wfc[jj], xfc[mi], acc[jj][mi], 0, 0, 0);
                if (ks < 11) {
                    #pragma unroll
                    for (int jj = 0; jj < 3; ++jj) wfc[jj] = wfn[jj];
                    #pragma unroll
                    for (int mi = 0; mi < 4; ++mi) xfc[mi] = xfn[mi];
                }
            }
            // epilogue A: (chan=ct*16+q4*4+r, tok=l15) -> q/k [tok][chan]
            #pragma unroll
            for (int jj = 0; jj < 3; ++jj) {
                const int ct = tb0 + jj;
                const int c0 = ct * 16 + q4 * 4;
                float4 bv = *(const float4*)(qkv_b + c0);
                bf16_t* dst = (ct < 24) ? qa : ka;
                const int cc = c0 - (ct < 24 ? 0 : C_);
                #pragma unroll
                for (int mi = 0; mi < 4; ++mi) {
                    const int m = mi * 16 + l15;
                    if (m < N_) {
                        bf16x4 o;
                        o[0] = (bf16_t)(acc[jj][mi][0] + bv.x);
                        o[1] = (bf16_t)(acc[jj][mi][1] + bv.y);
                        o[2] = (bf16_t)(acc[jj][mi][2] + bv.z);
                        o[3] = (bf16_t)(acc[jj][mi][3] + bv.w);
                        *(bf16x4*)(dst + m * XS_STRIDE + cc) = o;
                    }
                }
            }
        }
    } else {
        #pragma unroll
        for (int p = 0; p < 2; ++p) {
            const int tb0 = 48 + (wave - 8) * 6 + p * 3;
            f32x4 acc[3][4];
            #pragma unroll
            for (int jj = 0; jj < 3; ++jj)
                #pragma unroll
                for (int mi = 0; mi < 4; ++mi) acc[jj][mi] = z4;

            bf16x8 wfc[3], xfc[4];
            #pragma unroll
            for (int jj = 0; jj < 3; ++jj)
                wfc[jj] = *(const bf16x8*)(wqkvT +
                    ((size_t)((tb0 + jj) * 12 + 0) * 64 + lane) * 8);
            #pragma unroll
            for (int mi = 0; mi < 4; ++mi)
                xfc[mi] = *(const bf16x8*)(xs + (mi * 16 + l15) * XS_STRIDE + q4 * 8);

            #pragma unroll
            for (int ks = 0; ks < 12; ++ks) {
                bf16x8 wfn[3], xfn[4];
                if (ks < 11) {
                    #pragma unroll
                    for (int jj = 0; jj < 3; ++jj)
                        wfn[jj] = *(const bf16x8*)(wqkvT +
                            ((size_t)((tb0 + jj) * 12 + ks + 1) * 64 + lane) * 8);
                    #pragma unroll
                    for (int mi = 0; mi < 4; ++mi)
                        xfn[mi] = *(const bf16x8*)(xs + (mi * 16 + l15) * XS_STRIDE
                                                      + (ks + 1) * 32 + q4 * 8);
                }
                #pragma unroll
                for (int jj = 0; jj < 3; ++jj)
                    #pragma unroll
                    for (int mi = 0; mi < 4; ++mi)
                        acc[jj][mi] = __builtin_amdgcn_mfma_f32_16x16x32_bf16(
                            xfc[mi], wfc[jj], acc[jj][mi], 0, 0, 0);
                if (ks < 11) {
                    #pragma unroll
                    for (int jj = 0; jj < 3; ++jj) wfc[jj] = wfn[jj];
                    #pragma unroll
                    for (int mi = 0; mi < 4; ++mi) xfc[mi] = xfn[mi];
                }
            }
            // epilogue B: (tok=q4*4+r+mi*16, chan=ct*16+l15) -> vT [dim][tok]
            #pragma unroll
            for (int jj = 0; jj < 3; ++jj) {
                const int ct = tb0 + jj;         // 48..71
                const int c  = ct * 16 + l15;
                const int d  = c - 2 * C_;       // v dim 0..383
                const float bb = qkv_b[c];
                #pragma unroll
                for (int mi = 0; mi < 4; ++mi) {
                    const int t0 = mi * 16 + q4 * 4;
                    if (t0 + 3 < N_) {
                        bf16x4 o;
                        #pragma unroll
                        for (int r = 0; r < 4; ++r) o[r] = (bf16_t)(acc[jj][mi][r] + bb);
                        *(bf16x4*)(vt + d * VT_STRIDE + t0) = o;
                    } else {
                        #pragma unroll
                        for (int r = 0; r < 4; ++r)
                            if (t0 + r < N_)
                                vt[d * VT_STRIDE + t0 + r] = (bf16_t)(acc[jj][mi][r] + bb);
                    }
                }
            }
        }
    }
    __syncthreads();

    // ---------------- phase 3: attention, wave = head, pipelined ----------
    // ao staged inline: wave h touches only qa cols [h*32,h*32+32) (private);
    // ao rows written at step mt (mt*16..+15) are never re-read by the
    // qf(mt+1) load (rows mt*16+16..+31) — disjoint.
    {
        bf16_t* pb = (bf16_t*)(smem + wave * 2304);   // 16 x 72 bf16 (xs dead)
        const bf16_t* tb = btbl + (size_t)((b & (NW_ - 1)) * H_ + wave) * (N_ * 64);
        const float SC = 0.17677669529663687f * 1.4426950408889634f;

        // K and V fragments for this head: loaded once, reused for all steps
        bf16x8 kf[4];
        #pragma unroll
        for (int ni = 0; ni < 4; ++ni)
            kf[ni] = *(const bf16x8*)(ka + (ni * 16 + l15) * XS_STRIDE
                                         + wave * D_ + q4 * 8);
        bf16x8 vf[2][2];
        #pragma unroll
        for (int ks2 = 0; ks2 < 2; ++ks2)
            #pragma unroll
            for (int dt = 0; dt < 2; ++dt)
                vf[ks2][dt] = *(const bf16x8*)(vt + (wave * D_ + dt * 16 + l15) * VT_STRIDE
                                                  + ks2 * 32 + q4 * 8);

        // prologue: QK(0)
        bf16x8 qf0 = *(const bf16x8*)(qa + (0 * 16 + l15) * XS_STRIDE
                                         + wave * D_ + q4 * 8);
        f32x4 sA[4], sB[4];
        #pragma unroll
        for (int ni = 0; ni < 4; ++ni)
            sA[ni] = __builtin_amdgcn_mfma_f32_16x16x32_bf16(kf[ni], qf0, z4, 0, 0, 0);

        P3_STEP(0, sA, sB, 0)
        P3_STEP(1, sB, sA, 0)
        P3_STEP(2, sA, sB, 0)
        P3_STEP(3, sB, sA, 1)
    }
    __syncthreads();   // ao complete (all columns) before P4 reads qa

    // ---------------- phase 4: out = ao @ Wproj + b, 2 tiles/wave ---------
    {
        f32x4 pacc[2][4];
        #pragma unroll
        for (int jj = 0; jj < 2; ++jj)
            #pragma unroll
            for (int mi = 0; mi < 4; ++mi) pacc[jj][mi] = z4;

        bf16x8 wfc[2], afc[4];
        #pragma unroll
        for (int jj = 0; jj < 2; ++jj)
            wfc[jj] = *(const bf16x8*)(wprojT +
                ((size_t)((wave * 2 + jj) * 12 + 0) * 64 + lane) * 8);
        #pragma unroll
        for (int mi = 0; mi < 4; ++mi)
            afc[mi] = *(const bf16x8*)(qa + (mi * 16 + l15) * XS_STRIDE + q4 * 8);

        #pragma unroll
        for (int ks = 0; ks < 12; ++ks) {
            bf16x8 wfn[2], afn[4];
            if (ks < 11) {
                #pragma unroll
                for (int jj = 0; jj < 2; ++jj)
                    wfn[jj] = *(const bf16x8*)(wprojT +
                        ((size_t)((wave * 2 + jj) * 12 + ks + 1) * 64 + lane) * 8);
                #pragma unroll
                for (int mi = 0; mi < 4; ++mi)
                    afn[mi] = *(const bf16x8*)(qa + (mi * 16 + l15) * XS_STRIDE
                                                  + (ks + 1) * 32 + q4 * 8);
            }
            #pragma unroll
            for (int jj = 0; jj < 2; ++jj)
                #pragma unroll
                for (int mi = 0; mi < 4; ++mi)
                    pacc[jj][mi] = __builtin_amdgcn_mfma_f32_16x16x32_bf16(
                        afc[mi], wfc[jj], pacc[jj][mi], 0, 0, 0);
            if (ks < 11) {
                #pragma unroll
                for (int jj = 0; jj < 2; ++jj) wfc[jj] = wfn[jj];
                #pragma unroll
                for (int mi = 0; mi < 4; ++mi) afc[mi] = afn[mi];
            }
        }
        float* og = out + (size_t)b * (N_ * C_);
        #pragma unroll
        for (int jj = 0; jj < 2; ++jj) {
            const int n = (wave * 2 + jj) * 16 + l15;
            const float bias = proj_b[n];
            #pragma unroll
            for (int mi = 0; mi < 4; ++mi) {
                #pragma unroll
                for (int r = 0; r < 4; ++r) {
                    const int m = mi * 16 + q4 * 4 + r;
                    if (m < N_) og[m * C_ + n] = pacc[jj][mi][r] + bias;
                }
            }
        }
    }
}

// ---------------------------------------------------------------------------
extern "C" void kernel_launch(void* const* d_in, const int* in_sizes, int n_in,
                              void* d_out, int out_size, void* d_ws, size_t ws_size,
                              hipStream_t stream)
{
    const float* x      = (const float*)d_in[0];
    const float* mask   = (const float*)d_in[1];
    const float* qkv_w  = (const float*)d_in[2];
    const float* qkv_b  = (const float*)d_in[3];
    const float* proj_w = (const float*)d_in[4];
    const float* proj_b = (const float*)d_in[5];
    const float* rpb    = (const float*)d_in[6];
    float* out = (float*)d_out;

    bf16_t* wqkvT  = (bf16_t*)d_ws;
    bf16_t* wprojT = wqkvT + WQKV_ELEMS;
    bf16_t* btbl   = wprojT + WPROJ_ELEMS;   // 64*12*49*64 bf16 = 4.8 MB

    prep_all<<<288 + NW_ * H_, 256, 0, stream>>>(qkv_w, proj_w, mask, rpb,
                                                 wqkvT, wprojT, btbl);
    fused_window_attn<<<2048, 768, 0, stream>>>(x, qkv_b, proj_b,
                                                wqkvT, wprojT, btbl, out);
}

// Round 8
// 467.003 us; speedup vs baseline: 2.8685x; 1.0122x over previous
//
#include <hip/hip_runtime.h>
#include <stdint.h>
#include <stddef.h>

typedef __bf16 bf16_t;
typedef __bf16 bf16x4 __attribute__((ext_vector_type(4)));
typedef __bf16 bf16x8 __attribute__((ext_vector_type(8)));
typedef float  f32x4  __attribute__((ext_vector_type(4)));

#define H_   12
#define N_   49
#define C_   384
#define D_   32
#define NW_  64
#define C3_  1152

// ---- LDS layout (bytes) ----
// xs: 49 x 392 bf16 (38416 B) — shared x tile, read-only after B0.
// 12 per-wave arenas (9856 B each): private to wave h = head h.
//   q  [49][32] (3136 B) — q in P3, overlaid by ao after qf hoist
//   k  [49][32] (3136 B) — k in P3, overlaid by P buffer after kf hoist
//   vT [32][56] (3584 B) — v^T [dim][tok], cols 48..55 zeroed
// +16 B tail guard (last arena's vT b128 overrun).
#define XS_STRIDE 392
#define ARENA_OFF 38416
#define ARENA_SZ  9856
#define AK_OFF    3136
#define AV_OFF    6272
#define AV_STRIDE 56
#define P_STRIDE  72
#define SMEM_BYTES 156704        // 38416 + 12*9856 + 16

#define WQKV_ELEMS  (C3_ * C_)   // 442368
#define WPROJ_ELEMS (C_ * C_)    // 147456

// padded row clamp: tile mi==3 covers toks 48..63; clamp to 48 (broadcast).
// Junk outputs are masked by the existing m<N_ / t0<N_ guards downstream.
#define XF_ROW(mi) ((mi) == 3 ? 48 : (mi) * 16 + l15)

// ---------------------------------------------------------------------------
// prep_all: merged weight transpose + bias table build (one launch).
// blocks 0..287: frag-order transpose of qkv_w/proj_w.
// blocks 288..1055: btbl[w][h][m][n] = (rpb+mask)*log2e, n padded to 64.
// ---------------------------------------------------------------------------
__global__ void prep_all(const float* __restrict__ qkv_w,
                         const float* __restrict__ proj_w,
                         const float* __restrict__ mask,
                         const float* __restrict__ rpb,
                         bf16_t* __restrict__ wqkvT,
                         bf16_t* __restrict__ wprojT,
                         bf16_t* __restrict__ btbl)
{
    __shared__ bf16_t tile[32][72];
    int bid = blockIdx.x;
    const int t = threadIdx.x;
    if (bid < 288) {
        const float* src; bf16_t* dst; int NC, ks, g;
        if (bid < 216) { src = qkv_w;  dst = wqkvT;  NC = C3_; ks = bid % 12; g = bid / 12; }
        else { bid -= 216; src = proj_w; dst = wprojT; NC = C_;  ks = bid % 12; g = bid / 12; }
        const int n0 = g * 64;
        const int r0 = t >> 6, cc = t & 63;
        #pragma unroll
        for (int p = 0; p < 8; ++p) {
            int row = p * 4 + r0;
            tile[row][cc] = (bf16_t)src[(ks * 32 + row) * NC + n0 + cc];
        }
        __syncthreads();
        const int lane = t & 63, ctl = t >> 6;
        const int q4 = lane >> 4, l15 = lane & 15;
        bf16x8 v;
        #pragma unroll
        for (int j = 0; j < 8; ++j) v[j] = tile[q4 * 8 + j][ctl * 16 + l15];
        *(bf16x8*)(dst + ((size_t)((g * 4 + ctl) * 12 + ks) * 64 + lane) * 8) = v;
    } else {
        bid -= 288;
        const int w = bid / H_, h = bid % H_;
        bf16_t* out = btbl + (size_t)(w * H_ + h) * (N_ * 64);
        for (int idx = t; idx < N_ * 64; idx += 256) {
            int m = idx >> 6, n = idx & 63;
            float v = 0.f;
            if (n < N_)
                v = (rpb[(h * N_ + m) * N_ + n] + mask[((size_t)w * N_ + m) * N_ + n])
                    * 1.4426950408889634f;
            out[idx] = (bf16_t)v;
        }
    }
}

// ---------------------------------------------------------------------------
// Head-decoupled fused kernel: one block per window, 12 waves. Wave h owns
// head h end-to-end: it computes q/k/v channels h*32..h*32+31 (tiles 2h,2h+1,
// 24+2h,24+2h+1,48+2h,48+2h+1) into its PRIVATE arena, then runs attention
// for head h with NO barrier (same-wave LDS ordering). Waves skew naturally,
// interleaving P2's L2-bound phase with P3's VALU-bound phase across the CU.
// Barriers: B0 (xs staged) and B1 (all ao ready) only.
// ---------------------------------------------------------------------------
__global__ __launch_bounds__(768, 3)
void fused_window_attn(const float* __restrict__ x,
                       const float* __restrict__ qkv_b,
                       const float* __restrict__ proj_b,
                       const bf16_t* __restrict__ wqkvT,
                       const bf16_t* __restrict__ wprojT,
                       const bf16_t* __restrict__ btbl,
                       float* __restrict__ out)
{
    __shared__ __align__(16) unsigned char smem[SMEM_BYTES];
    bf16_t* xs = (bf16_t*)smem;

    const int tid  = threadIdx.x;
    const int wave = tid >> 6;                  // 0..11 = head
    const int lane = tid & 63;
    const int q4   = lane >> 4;
    const int l15  = lane & 15;
    const int b    = blockIdx.x;

    bf16_t* aq = (bf16_t*)(smem + ARENA_OFF + wave * ARENA_SZ);          // q/ao
    bf16_t* ak = (bf16_t*)(smem + ARENA_OFF + wave * ARENA_SZ + AK_OFF); // k/P
    bf16_t* av = (bf16_t*)(smem + ARENA_OFF + wave * ARENA_SZ + AV_OFF); // vT

    const f32x4 z4 = {0.f, 0.f, 0.f, 0.f};

    // ---------------- P1: zero own vT pad cols; stage x -> xs -------------
    {
        // vT cols 48..55 must be exact zeros (read x P==0 by PV b128;
        // 0*NaN = NaN). Epilogue B never writes cols >= 49.
        for (int t = lane; t < 256; t += 64) {
            int r = t >> 3, c = t & 7;
            av[r * AV_STRIDE + 48 + c] = (bf16_t)0.f;
        }
        if (tid < 8) ((bf16_t*)(smem + SMEM_BYTES - 16))[tid] = (bf16_t)0.f;

        const float* xg = x + (size_t)b * (N_ * C_);
        for (int t = tid; t < (N_ * C_) / 4; t += 768) {
            float4 v = ((const float4*)xg)[t];
            int r = t / 96, c4 = t % 96;
            bf16x4 o;
            o[0] = (bf16_t)v.x; o[1] = (bf16_t)v.y;
            o[2] = (bf16_t)v.z; o[3] = (bf16_t)v.w;
            *(bf16x4*)(xs + r * XS_STRIDE + c4 * 4) = o;
        }
    }
    __syncthreads();   // B0: xs ready for all waves

    // ---------------- P2 pass 0: tiles {2h, 2h+1, 24+2h}, all A-type ------
    {
        const int tA0 = 2 * wave, tA1 = 2 * wave + 1, tA2 = 24 + 2 * wave;
        f32x4 acc[3][4];
        #pragma unroll
        for (int jj = 0; jj < 3; ++jj)
            #pragma unroll
            for (int mi = 0; mi < 4; ++mi) acc[jj][mi] = z4;

        bf16x8 wfc[3], xfc[4];
        wfc[0] = *(const bf16x8*)(wqkvT + ((size_t)(tA0 * 12) * 64 + lane) * 8);
        wfc[1] = *(const bf16x8*)(wqkvT + ((size_t)(tA1 * 12) * 64 + lane) * 8);
        wfc[2] = *(const bf16x8*)(wqkvT + ((size_t)(tA2 * 12) * 64 + lane) * 8);
        #pragma unroll
        for (int mi = 0; mi < 4; ++mi)
            xfc[mi] = *(const bf16x8*)(xs + XF_ROW(mi) * XS_STRIDE + q4 * 8);

        #pragma unroll
        for (int ks = 0; ks < 12; ++ks) {
            bf16x8 wfn[3], xfn[4];
            if (ks < 11) {
                wfn[0] = *(const bf16x8*)(wqkvT + ((size_t)(tA0 * 12 + ks + 1) * 64 + lane) * 8);
                wfn[1] = *(const bf16x8*)(wqkvT + ((size_t)(tA1 * 12 + ks + 1) * 64 + lane) * 8);
                wfn[2] = *(const bf16x8*)(wqkvT + ((size_t)(tA2 * 12 + ks + 1) * 64 + lane) * 8);
                #pragma unroll
                for (int mi = 0; mi < 4; ++mi)
                    xfn[mi] = *(const bf16x8*)(xs + XF_ROW(mi) * XS_STRIDE
                                                  + (ks + 1) * 32 + q4 * 8);
            }
            #pragma unroll
            for (int jj = 0; jj < 3; ++jj)
                #pragma unroll
                for (int mi = 0; mi < 4; ++mi)
                    acc[jj][mi] = __builtin_amdgcn_mfma_f32_16x16x32_bf16(
                        wfc[jj], xfc[mi], acc[jj][mi], 0, 0, 0);
            if (ks < 11) {
                #pragma unroll
                for (int jj = 0; jj < 3; ++jj) wfc[jj] = wfn[jj];
                #pragma unroll
                for (int mi = 0; mi < 4; ++mi) xfc[mi] = xfn[mi];
            }
        }
        // epilogue A: jj0,jj1 -> q arena (local col jj*16+q4*4); jj2 -> k col q4*4
        #pragma unroll
        for (int jj = 0; jj < 3; ++jj) {
            const int gt = (jj < 2) ? (2 * wave + jj) : (24 + 2 * wave);
            const int gc = gt * 16 + q4 * 4;
            bf16_t* dst = (jj < 2) ? aq : ak;
            const int cl = (jj < 2) ? (jj * 16 + q4 * 4) : (q4 * 4);
            float4 bv = *(const float4*)(qkv_b + gc);
            #pragma unroll
            for (int mi = 0; mi < 4; ++mi) {
                const int m = mi * 16 + l15;
                if (m < N_) {
                    bf16x4 o;
                    o[0] = (bf16_t)(acc[jj][mi][0] + bv.x);
                    o[1] = (bf16_t)(acc[jj][mi][1] + bv.y);
                    o[2] = (bf16_t)(acc[jj][mi][2] + bv.z);
                    o[3] = (bf16_t)(acc[jj][mi][3] + bv.w);
                    *(bf16x4*)(dst + m * 32 + cl) = o;
                }
            }
        }
    }

    // ---------------- P2 pass 1: {24+2h+1 (A), 48+2h (B), 48+2h+1 (B)} ----
    {
        const int tA = 24 + 2 * wave + 1;
        const int tB0 = 48 + 2 * wave, tB1 = 48 + 2 * wave + 1;
        f32x4 acc[3][4];
        #pragma unroll
        for (int jj = 0; jj < 3; ++jj)
            #pragma unroll
            for (int mi = 0; mi < 4; ++mi) acc[jj][mi] = z4;

        bf16x8 wfc[3], xfc[4];
        wfc[0] = *(const bf16x8*)(wqkvT + ((size_t)(tA * 12) * 64 + lane) * 8);
        wfc[1] = *(const bf16x8*)(wqkvT + ((size_t)(tB0 * 12) * 64 + lane) * 8);
        wfc[2] = *(const bf16x8*)(wqkvT + ((size_t)(tB1 * 12) * 64 + lane) * 8);
        #pragma unroll
        for (int mi = 0; mi < 4; ++mi)
            xfc[mi] = *(const bf16x8*)(xs + XF_ROW(mi) * XS_STRIDE + q4 * 8);

        #pragma unroll
        for (int ks = 0; ks < 12; ++ks) {
            bf16x8 wfn[3], xfn[4];
            if (ks < 11) {
                wfn[0] = *(const bf16x8*)(wqkvT + ((size_t)(tA * 12 + ks + 1) * 64 + lane) * 8);
                wfn[1] = *(const bf16x8*)(wqkvT + ((size_t)(tB0 * 12 + ks + 1) * 64 + lane) * 8);
                wfn[2] = *(const bf16x8*)(wqkvT + ((size_t)(tB1 * 12 + ks + 1) * 64 + lane) * 8);
                #pragma unroll
                for (int mi = 0; mi < 4; ++mi)
                    xfn[mi] = *(const bf16x8*)(xs + XF_ROW(mi) * XS_STRIDE
                                                  + (ks + 1) * 32 + q4 * 8);
            }
            #pragma unroll
            for (int mi = 0; mi < 4; ++mi) {
                acc[0][mi] = __builtin_amdgcn_mfma_f32_16x16x32_bf16(
                    wfc[0], xfc[mi], acc[0][mi], 0, 0, 0);      // A-type (k1)
                acc[1][mi] = __builtin_amdgcn_mfma_f32_16x16x32_bf16(
                    xfc[mi], wfc[1], acc[1][mi], 0, 0, 0);      // B-type (v0)
                acc[2][mi] = __builtin_amdgcn_mfma_f32_16x16x32_bf16(
                    xfc[mi], wfc[2], acc[2][mi], 0, 0, 0);      // B-type (v1)
            }
            if (ks < 11) {
                #pragma unroll
                for (int jj = 0; jj < 3; ++jj) wfc[jj] = wfn[jj];
                #pragma unroll
                for (int mi = 0; mi < 4; ++mi) xfc[mi] = xfn[mi];
            }
        }
        // epilogue A for k1 -> k arena local col 16+q4*4
        {
            const int gc = tA * 16 + q4 * 4;
            float4 bv = *(const float4*)(qkv_b + gc);
            #pragma unroll
            for (int mi = 0; mi < 4; ++mi) {
                const int m = mi * 16 + l15;
                if (m < N_) {
                    bf16x4 o;
                    o[0] = (bf16_t)(acc[0][mi][0] + bv.x);
                    o[1] = (bf16_t)(acc[0][mi][1] + bv.y);
                    o[2] = (bf16_t)(acc[0][mi][2] + bv.z);
                    o[3] = (bf16_t)(acc[0][mi][3] + bv.w);
                    *(bf16x4*)(ak + m * 32 + 16 + q4 * 4) = o;
                }
            }
        }
        // epilogue B for v0,v1 -> vT arena [dim local][tok]
        #pragma unroll
        for (int jv = 0; jv < 2; ++jv) {
            const int d  = jv * 16 + l15;                       // local dim
            const float bb = qkv_b[(48 + 2 * wave + jv) * 16 + l15];
            #pragma unroll
            for (int mi = 0; mi < 4; ++mi) {
                const int t0 = mi * 16 + q4 * 4;
                if (t0 + 3 < N_) {
                    bf16x4 o;
                    #pragma unroll
                    for (int r = 0; r < 4; ++r) o[r] = (bf16_t)(acc[1 + jv][mi][r] + bb);
                    *(bf16x4*)(av + d * AV_STRIDE + t0) = o;
                } else {
                    #pragma unroll
                    for (int r = 0; r < 4; ++r)
                        if (t0 + r < N_)
                            av[d * AV_STRIDE + t0 + r] = (bf16_t)(acc[1 + jv][mi][r] + bb);
                }
            }
        }
    }
    // NO barrier: wave h's arena is complete; proceed straight to attention.

    // ---------------- P3: attention for head h (private arena) ------------
    {
        bf16_t* pb = ak;   // P overlays k arena (dead after kf hoist below)
        const bf16_t* tb = btbl + (size_t)((b & (NW_ - 1)) * H_ + wave) * (N_ * 64);
        const float SC = 0.17677669529663687f * 1.4426950408889634f;

        bf16x8 kf[4];
        #pragma unroll
        for (int ni = 0; ni < 4; ++ni) {
            const int kr = (ni == 3) ? 48 : ni * 16 + l15;
            kf[ni] = *(const bf16x8*)(ak + kr * 32 + q4 * 8);
        }
        bf16x8 vf[2][2];
        #pragma unroll
        for (int ks2 = 0; ks2 < 2; ++ks2)
            #pragma unroll
            for (int dt = 0; dt < 2; ++dt)
                vf[ks2][dt] = *(const bf16x8*)(av + (dt * 16 + l15) * AV_STRIDE
                                                  + ks2 * 32 + q4 * 8);
        bf16x8 qf[4];
        #pragma unroll
        for (int mt = 0; mt < 4; ++mt) {
            const int qr = (mt == 3) ? 48 : mt * 16 + l15;
            qf[mt] = *(const bf16x8*)(aq + qr * 32 + q4 * 8);
        }
        // aq dead as q; ao overlays it below.

        #pragma unroll
        for (int mt = 0; mt < 4; ++mt) {
            f32x4 sacc[4];
            #pragma unroll
            for (int ni = 0; ni < 4; ++ni)
                sacc[ni] = __builtin_amdgcn_mfma_f32_16x16x32_bf16(
                    kf[ni], qf[mt], z4, 0, 0, 0);

            const int m  = mt * 16 + l15;
            const int mc = m < 48 ? m : 48;
            float den = 0.f;
            #pragma unroll
            for (int ni = 0; ni < 4; ++ni) {
                bf16x4 bv = *(const bf16x4*)(tb + (size_t)mc * 64 + ni * 16 + q4 * 4);
                #pragma unroll
                for (int r = 0; r < 4; ++r) {
                    const int n = ni * 16 + q4 * 4 + r;
                    float s = 0.f;
                    if (n < N_)
                        s = __builtin_exp2f(sacc[ni][r] * SC + (float)bv[r]);
                    sacc[ni][r] = s;
                    den += s;
                }
            }
            den += __shfl_xor(den, 16);
            den += __shfl_xor(den, 32);
            const float ri = __builtin_amdgcn_rcpf(den);

            // P write (exact zeros for n>=49; rows m>=49 skipped -> stale,
            // masked at ao staging)
            if (m < N_) {
                #pragma unroll
                for (int ni = 0; ni < 4; ++ni) {
                    bf16x4 o;
                    #pragma unroll
                    for (int r = 0; r < 4; ++r) o[r] = (bf16_t)(sacc[ni][r] * ri);
                    *(bf16x4*)(pb + l15 * P_STRIDE + ni * 16 + q4 * 4) = o;
                }
            }

            f32x4 o0 = z4, o1 = z4;
            #pragma unroll
            for (int ks2 = 0; ks2 < 2; ++ks2) {
                bf16x8 pf = *(const bf16x8*)(pb + l15 * P_STRIDE + ks2 * 32 + q4 * 8);
                o0 = __builtin_amdgcn_mfma_f32_16x16x32_bf16(pf, vf[ks2][0], o0, 0, 0, 0);
                o1 = __builtin_amdgcn_mfma_f32_16x16x32_bf16(pf, vf[ks2][1], o1, 0, 0, 0);
            }
            #pragma unroll
            for (int r = 0; r < 4; ++r) {
                const int ms = mt * 16 + q4 * 4 + r;
                if (ms < N_) {
                    aq[ms * 32 + l15]      = (bf16_t)o0[r];
                    aq[ms * 32 + 16 + l15] = (bf16_t)o1[r];
                }
            }
        }
    }
    __syncthreads();   // B1: all heads' ao staged in arenas

    // ---------------- P4: out = ao @ Wproj + b, 2 col-tiles/wave ----------
    {
        f32x4 pacc[2][4];
        #pragma unroll
        for (int jj = 0; jj < 2; ++jj)
            #pragma unroll
            for (int mi = 0; mi < 4; ++mi) pacc[jj][mi] = z4;

        bf16x8 wfc[2], afc[4];
        #pragma unroll
        for (int jj = 0; jj < 2; ++jj)
            wfc[jj] = *(const bf16x8*)(wprojT +
                ((size_t)((wave * 2 + jj) * 12 + 0) * 64 + lane) * 8);
        #pragma unroll
        for (int mi = 0; mi < 4; ++mi)
            afc[mi] = *(const bf16x8*)((bf16_t*)(smem + ARENA_OFF)
                                       + XF_ROW(mi) * 32 + q4 * 8);

        #pragma unroll
        for (int ks = 0; ks < 12; ++ks) {
            bf16x8 wfn[2], afn[4];
            if (ks < 11) {
                #pragma unroll
                for (int jj = 0; jj < 2; ++jj)
                    wfn[jj] = *(const bf16x8*)(wprojT +
                        ((size_t)((wave * 2 + jj) * 12 + ks + 1) * 64 + lane) * 8);
                bf16_t* an = (bf16_t*)(smem + ARENA_OFF + (ks + 1) * ARENA_SZ);
                #pragma unroll
                for (int mi = 0; mi < 4; ++mi)
                    afn[mi] = *(const bf16x8*)(an + XF_ROW(mi) * 32 + q4 * 8);
            }
            #pragma unroll
            for (int jj = 0; jj < 2; ++jj)
                #pragma unroll
                for (int mi = 0; mi < 4; ++mi)
                    pacc[jj][mi] = __builtin_amdgcn_mfma_f32_16x16x32_bf16(
                        afc[mi], wfc[jj], pacc[jj][mi], 0, 0, 0);
            if (ks < 11) {
                #pragma unroll
                for (int jj = 0; jj < 2; ++jj) wfc[jj] = wfn[jj];
                #pragma unroll
                for (int mi = 0; mi < 4; ++mi) afc[mi] = afn[mi];
            }
        }
        float* og = out + (size_t)b * (N_ * C_);
        #pragma unroll
        for (int jj = 0; jj < 2; ++jj) {
            const int n = (wave * 2 + jj) * 16 + l15;
            const float bias = proj_b[n];
            #pragma unroll
            for (int mi = 0; mi < 4; ++mi) {
                #pragma unroll
                for (int r = 0; r < 4; ++r) {
                    const int m = mi * 16 + q4 * 4 + r;
                    if (m < N_) og[m * C_ + n] = pacc[jj][mi][r] + bias;
                }
            }
        }
    }
}

// ---------------------------------------------------------------------------
extern "C" void kernel_launch(void* const* d_in, const int* in_sizes, int n_in,
                              void* d_out, int out_size, void* d_ws, size_t ws_size,
                              hipStream_t stream)
{
    const float* x      = (const float*)d_in[0];
    const float* mask   = (const float*)d_in[1];
    const float* qkv_w  = (const float*)d_in[2];
    const float* qkv_b  = (const float*)d_in[3];
    const float* proj_w = (const float*)d_in[4];
    const float* proj_b = (const float*)d_in[5];
    const float* rpb    = (const float*)d_in[6];
    float* out = (float*)d_out;

    bf16_t* wqkvT  = (bf16_t*)d_ws;
    bf16_t* wprojT = wqkvT + WQKV_ELEMS;
    bf16_t* btbl   = wprojT + WPROJ_ELEMS;   // 64*12*49*64 bf16 = 4.8 MB

    prep_all<<<288 + NW_ * H_, 256, 0, stream>>>(qkv_w, proj_w, mask, rpb,
                                                 wqkvT, wprojT, btbl);
    fused_window_attn<<<2048, 768, 0, stream>>>(x, qkv_b, proj_b,
                                                wqkvT, wprojT, btbl, out);
}

// Round 9
// 456.168 us; speedup vs baseline: 2.9367x; 1.0238x over previous
//
#include <hip/hip_runtime.h>
#include <stdint.h>
#include <stddef.h>

typedef __bf16 bf16_t;
typedef __bf16 bf16x4 __attribute__((ext_vector_type(4)));
typedef __bf16 bf16x8 __attribute__((ext_vector_type(8)));
typedef float  f32x4  __attribute__((ext_vector_type(4)));

#define H_   12
#define N_   49
#define C_   384
#define D_   32
#define NW_  64
#define C3_  1152

// ---- LDS layout (bytes) ----
// xs: 49 x 392 bf16 (38416 B) — shared x tile, read-only after B0.
// 12 per-wave arenas (9856 B each): private to wave h = head h.
//   bytes 0..3135  : q  [49][32] (stride 32) — read by qf hoist only
//   bytes 3136..6271: k [49][32] (stride 32) — read by kf hoist only
//   bytes 6272..9855: vT [32][56]            — cols 48..55 zeroed
// After the qf/kf hoists (P3 start), the arena is repurposed:
//   ao [49][40] (stride 40 -> bank-conflict-free b128 reads in P4):
//       bytes 0..3919  (q region + first 784 B of k)
//   P  16 x 72 elems: bytes 3920..6223  (k + 784, disjoint from ao)
// +16 B tail guard (last arena's vT b128 overrun).
#define XS_STRIDE 392
#define ARENA_OFF 38416
#define ARENA_SZ  9856
#define AK_OFF    3136
#define AV_OFF    6272
#define AV_STRIDE 56
#define AO_STRIDE 40            // elems; 80 B rows -> bank step 20 -> 2-way max
#define P_STRIDE  72
#define SMEM_BYTES 156704        // 38416 + 12*9856 + 16

#define WQKV_ELEMS  (C3_ * C_)   // 442368
#define WPROJ_ELEMS (C_ * C_)    // 147456

// padded row clamp: tile mi==3 covers toks 48..63; clamp to 48 (broadcast).
// Junk outputs are masked by the existing m<N_ / t0<N_ guards downstream.
#define XF_ROW(mi) ((mi) == 3 ? 48 : (mi) * 16 + l15)

// ---------------------------------------------------------------------------
// prep_all: merged weight transpose + bias table build (one launch).
// blocks 0..287: frag-order transpose of qkv_w/proj_w.
// blocks 288..1055: btbl[w][h][m][n] = (rpb+mask)*log2e, n padded to 64.
// ---------------------------------------------------------------------------
__global__ void prep_all(const float* __restrict__ qkv_w,
                         const float* __restrict__ proj_w,
                         const float* __restrict__ mask,
                         const float* __restrict__ rpb,
                         bf16_t* __restrict__ wqkvT,
                         bf16_t* __restrict__ wprojT,
                         bf16_t* __restrict__ btbl)
{
    __shared__ bf16_t tile[32][72];
    int bid = blockIdx.x;
    const int t = threadIdx.x;
    if (bid < 288) {
        const float* src; bf16_t* dst; int NC, ks, g;
        if (bid < 216) { src = qkv_w;  dst = wqkvT;  NC = C3_; ks = bid % 12; g = bid / 12; }
        else { bid -= 216; src = proj_w; dst = wprojT; NC = C_;  ks = bid % 12; g = bid / 12; }
        const int n0 = g * 64;
        const int r0 = t >> 6, cc = t & 63;
        #pragma unroll
        for (int p = 0; p < 8; ++p) {
            int row = p * 4 + r0;
            tile[row][cc] = (bf16_t)src[(ks * 32 + row) * NC + n0 + cc];
        }
        __syncthreads();
        const int lane = t & 63, ctl = t >> 6;
        const int q4 = lane >> 4, l15 = lane & 15;
        bf16x8 v;
        #pragma unroll
        for (int j = 0; j < 8; ++j) v[j] = tile[q4 * 8 + j][ctl * 16 + l15];
        *(bf16x8*)(dst + ((size_t)((g * 4 + ctl) * 12 + ks) * 64 + lane) * 8) = v;
    } else {
        bid -= 288;
        const int w = bid / H_, h = bid % H_;
        bf16_t* out = btbl + (size_t)(w * H_ + h) * (N_ * 64);
        for (int idx = t; idx < N_ * 64; idx += 256) {
            int m = idx >> 6, n = idx & 63;
            float v = 0.f;
            if (n < N_)
                v = (rpb[(h * N_ + m) * N_ + n] + mask[((size_t)w * N_ + m) * N_ + n])
                    * 1.4426950408889634f;
            out[idx] = (bf16_t)v;
        }
    }
}

// ---------------------------------------------------------------------------
// Head-decoupled fused kernel: one block per window, 12 waves. Wave h owns
// head h end-to-end (private arena, no P2->P3 barrier; waves skew).
// This round: ao re-strided 32->40 elems (conflict-free P4 b128 reads);
// P buffer relocated to k+784B so ao's 784B spill into k is disjoint.
// Barriers: B0 (xs staged) and B1 (all ao ready) only.
// ---------------------------------------------------------------------------
__global__ __launch_bounds__(768, 3)
void fused_window_attn(const float* __restrict__ x,
                       const float* __restrict__ qkv_b,
                       const float* __restrict__ proj_b,
                       const bf16_t* __restrict__ wqkvT,
                       const bf16_t* __restrict__ wprojT,
                       const bf16_t* __restrict__ btbl,
                       float* __restrict__ out)
{
    __shared__ __align__(16) unsigned char smem[SMEM_BYTES];
    bf16_t* xs = (bf16_t*)smem;

    const int tid  = threadIdx.x;
    const int wave = tid >> 6;                  // 0..11 = head
    const int lane = tid & 63;
    const int q4   = lane >> 4;
    const int l15  = lane & 15;
    const int b    = blockIdx.x;

    bf16_t* aq = (bf16_t*)(smem + ARENA_OFF + wave * ARENA_SZ);          // q, then ao
    bf16_t* ak = (bf16_t*)(smem + ARENA_OFF + wave * ARENA_SZ + AK_OFF); // k, then P
    bf16_t* av = (bf16_t*)(smem + ARENA_OFF + wave * ARENA_SZ + AV_OFF); // vT

    const f32x4 z4 = {0.f, 0.f, 0.f, 0.f};

    // ---------------- P1: zero own vT pad cols; stage x -> xs -------------
    {
        // vT cols 48..55 must be exact zeros (read x P==0 by PV b128;
        // 0*NaN = NaN). Epilogue B never writes cols >= 49.
        for (int t = lane; t < 256; t += 64) {
            int r = t >> 3, c = t & 7;
            av[r * AV_STRIDE + 48 + c] = (bf16_t)0.f;
        }
        if (tid < 8) ((bf16_t*)(smem + SMEM_BYTES - 16))[tid] = (bf16_t)0.f;

        const float* xg = x + (size_t)b * (N_ * C_);
        for (int t = tid; t < (N_ * C_) / 4; t += 768) {
            float4 v = ((const float4*)xg)[t];
            int r = t / 96, c4 = t % 96;
            bf16x4 o;
            o[0] = (bf16_t)v.x; o[1] = (bf16_t)v.y;
            o[2] = (bf16_t)v.z; o[3] = (bf16_t)v.w;
            *(bf16x4*)(xs + r * XS_STRIDE + c4 * 4) = o;
        }
    }
    __syncthreads();   // B0: xs ready for all waves

    // ---------------- P2 pass 0: tiles {2h, 2h+1, 24+2h}, all A-type ------
    {
        const int tA0 = 2 * wave, tA1 = 2 * wave + 1, tA2 = 24 + 2 * wave;
        f32x4 acc[3][4];
        #pragma unroll
        for (int jj = 0; jj < 3; ++jj)
            #pragma unroll
            for (int mi = 0; mi < 4; ++mi) acc[jj][mi] = z4;

        bf16x8 wfc[3], xfc[4];
        wfc[0] = *(const bf16x8*)(wqkvT + ((size_t)(tA0 * 12) * 64 + lane) * 8);
        wfc[1] = *(const bf16x8*)(wqkvT + ((size_t)(tA1 * 12) * 64 + lane) * 8);
        wfc[2] = *(const bf16x8*)(wqkvT + ((size_t)(tA2 * 12) * 64 + lane) * 8);
        #pragma unroll
        for (int mi = 0; mi < 4; ++mi)
            xfc[mi] = *(const bf16x8*)(xs + XF_ROW(mi) * XS_STRIDE + q4 * 8);

        #pragma unroll
        for (int ks = 0; ks < 12; ++ks) {
            bf16x8 wfn[3], xfn[4];
            if (ks < 11) {
                wfn[0] = *(const bf16x8*)(wqkvT + ((size_t)(tA0 * 12 + ks + 1) * 64 + lane) * 8);
                wfn[1] = *(const bf16x8*)(wqkvT + ((size_t)(tA1 * 12 + ks + 1) * 64 + lane) * 8);
                wfn[2] = *(const bf16x8*)(wqkvT + ((size_t)(tA2 * 12 + ks + 1) * 64 + lane) * 8);
                #pragma unroll
                for (int mi = 0; mi < 4; ++mi)
                    xfn[mi] = *(const bf16x8*)(xs + XF_ROW(mi) * XS_STRIDE
                                                  + (ks + 1) * 32 + q4 * 8);
            }
            #pragma unroll
            for (int jj = 0; jj < 3; ++jj)
                #pragma unroll
                for (int mi = 0; mi < 4; ++mi)
                    acc[jj][mi] = __builtin_amdgcn_mfma_f32_16x16x32_bf16(
                        wfc[jj], xfc[mi], acc[jj][mi], 0, 0, 0);
            if (ks < 11) {
                #pragma unroll
                for (int jj = 0; jj < 3; ++jj) wfc[jj] = wfn[jj];
                #pragma unroll
                for (int mi = 0; mi < 4; ++mi) xfc[mi] = xfn[mi];
            }
        }
        // epilogue A: jj0,jj1 -> q arena (local col jj*16+q4*4); jj2 -> k col q4*4
        #pragma unroll
        for (int jj = 0; jj < 3; ++jj) {
            const int gt = (jj < 2) ? (2 * wave + jj) : (24 + 2 * wave);
            const int gc = gt * 16 + q4 * 4;
            bf16_t* dst = (jj < 2) ? aq : ak;
            const int cl = (jj < 2) ? (jj * 16 + q4 * 4) : (q4 * 4);
            float4 bv = *(const float4*)(qkv_b + gc);
            #pragma unroll
            for (int mi = 0; mi < 4; ++mi) {
                const int m = mi * 16 + l15;
                if (m < N_) {
                    bf16x4 o;
                    o[0] = (bf16_t)(acc[jj][mi][0] + bv.x);
                    o[1] = (bf16_t)(acc[jj][mi][1] + bv.y);
                    o[2] = (bf16_t)(acc[jj][mi][2] + bv.z);
                    o[3] = (bf16_t)(acc[jj][mi][3] + bv.w);
                    *(bf16x4*)(dst + m * 32 + cl) = o;
                }
            }
        }
    }

    // ---------------- P2 pass 1: {24+2h+1 (A), 48+2h (B), 48+2h+1 (B)} ----
    {
        const int tA = 24 + 2 * wave + 1;
        const int tB0 = 48 + 2 * wave, tB1 = 48 + 2 * wave + 1;
        f32x4 acc[3][4];
        #pragma unroll
        for (int jj = 0; jj < 3; ++jj)
            #pragma unroll
            for (int mi = 0; mi < 4; ++mi) acc[jj][mi] = z4;

        bf16x8 wfc[3], xfc[4];
        wfc[0] = *(const bf16x8*)(wqkvT + ((size_t)(tA * 12) * 64 + lane) * 8);
        wfc[1] = *(const bf16x8*)(wqkvT + ((size_t)(tB0 * 12) * 64 + lane) * 8);
        wfc[2] = *(const bf16x8*)(wqkvT + ((size_t)(tB1 * 12) * 64 + lane) * 8);
        #pragma unroll
        for (int mi = 0; mi < 4; ++mi)
            xfc[mi] = *(const bf16x8*)(xs + XF_ROW(mi) * XS_STRIDE + q4 * 8);

        #pragma unroll
        for (int ks = 0; ks < 12; ++ks) {
            bf16x8 wfn[3], xfn[4];
            if (ks < 11) {
                wfn[0] = *(const bf16x8*)(wqkvT + ((size_t)(tA * 12 + ks + 1) * 64 + lane) * 8);
                wfn[1] = *(const bf16x8*)(wqkvT + ((size_t)(tB0 * 12 + ks + 1) * 64 + lane) * 8);
                wfn[2] = *(const bf16x8*)(wqkvT + ((size_t)(tB1 * 12 + ks + 1) * 64 + lane) * 8);
                #pragma unroll
                for (int mi = 0; mi < 4; ++mi)
                    xfn[mi] = *(const bf16x8*)(xs + XF_ROW(mi) * XS_STRIDE
                                                  + (ks + 1) * 32 + q4 * 8);
            }
            #pragma unroll
            for (int mi = 0; mi < 4; ++mi) {
                acc[0][mi] = __builtin_amdgcn_mfma_f32_16x16x32_bf16(
                    wfc[0], xfc[mi], acc[0][mi], 0, 0, 0);      // A-type (k1)
                acc[1][mi] = __builtin_amdgcn_mfma_f32_16x16x32_bf16(
                    xfc[mi], wfc[1], acc[1][mi], 0, 0, 0);      // B-type (v0)
                acc[2][mi] = __builtin_amdgcn_mfma_f32_16x16x32_bf16(
                    xfc[mi], wfc[2], acc[2][mi], 0, 0, 0);      // B-type (v1)
            }
            if (ks < 11) {
                #pragma unroll
                for (int jj = 0; jj < 3; ++jj) wfc[jj] = wfn[jj];
                #pragma unroll
                for (int mi = 0; mi < 4; ++mi) xfc[mi] = xfn[mi];
            }
        }
        // epilogue A for k1 -> k arena local col 16+q4*4
        {
            const int gc = tA * 16 + q4 * 4;
            float4 bv = *(const float4*)(qkv_b + gc);
            #pragma unroll
            for (int mi = 0; mi < 4; ++mi) {
                const int m = mi * 16 + l15;
                if (m < N_) {
                    bf16x4 o;
                    o[0] = (bf16_t)(acc[0][mi][0] + bv.x);
                    o[1] = (bf16_t)(acc[0][mi][1] + bv.y);
                    o[2] = (bf16_t)(acc[0][mi][2] + bv.z);
                    o[3] = (bf16_t)(acc[0][mi][3] + bv.w);
                    *(bf16x4*)(ak + m * 32 + 16 + q4 * 4) = o;
                }
            }
        }
        // epilogue B for v0,v1 -> vT arena [dim local][tok]
        #pragma unroll
        for (int jv = 0; jv < 2; ++jv) {
            const int d  = jv * 16 + l15;                       // local dim
            const float bb = qkv_b[(48 + 2 * wave + jv) * 16 + l15];
            #pragma unroll
            for (int mi = 0; mi < 4; ++mi) {
                const int t0 = mi * 16 + q4 * 4;
                if (t0 + 3 < N_) {
                    bf16x4 o;
                    #pragma unroll
                    for (int r = 0; r < 4; ++r) o[r] = (bf16_t)(acc[1 + jv][mi][r] + bb);
                    *(bf16x4*)(av + d * AV_STRIDE + t0) = o;
                } else {
                    #pragma unroll
                    for (int r = 0; r < 4; ++r)
                        if (t0 + r < N_)
                            av[d * AV_STRIDE + t0 + r] = (bf16_t)(acc[1 + jv][mi][r] + bb);
                }
            }
        }
    }
    // NO barrier: wave h's arena is complete; proceed straight to attention.

    // ---------------- P3: attention for head h (private arena) ------------
    {
        bf16_t* pb = ak + 392;   // P at k+784 B (disjoint from ao's k spill)
        const bf16_t* tb = btbl + (size_t)((b & (NW_ - 1)) * H_ + wave) * (N_ * 64);
        const float SC = 0.17677669529663687f * 1.4426950408889634f;

        bf16x8 kf[4];
        #pragma unroll
        for (int ni = 0; ni < 4; ++ni) {
            const int kr = (ni == 3) ? 48 : ni * 16 + l15;
            kf[ni] = *(const bf16x8*)(ak + kr * 32 + q4 * 8);
        }
        bf16x8 vf[2][2];
        #pragma unroll
        for (int ks2 = 0; ks2 < 2; ++ks2)
            #pragma unroll
            for (int dt = 0; dt < 2; ++dt)
                vf[ks2][dt] = *(const bf16x8*)(av + (dt * 16 + l15) * AV_STRIDE
                                                  + ks2 * 32 + q4 * 8);
        bf16x8 qf[4];
        #pragma unroll
        for (int mt = 0; mt < 4; ++mt) {
            const int qr = (mt == 3) ? 48 : mt * 16 + l15;
            qf[mt] = *(const bf16x8*)(aq + qr * 32 + q4 * 8);
        }
        // q and k fully hoisted; arena repurposed: ao (stride 40) + P.

        #pragma unroll
        for (int mt = 0; mt < 4; ++mt) {
            f32x4 sacc[4];
            #pragma unroll
            for (int ni = 0; ni < 4; ++ni)
                sacc[ni] = __builtin_amdgcn_mfma_f32_16x16x32_bf16(
                    kf[ni], qf[mt], z4, 0, 0, 0);

            const int m  = mt * 16 + l15;
            const int mc = m < 48 ? m : 48;
            float den = 0.f;
            #pragma unroll
            for (int ni = 0; ni < 4; ++ni) {
                bf16x4 bv = *(const bf16x4*)(tb + (size_t)mc * 64 + ni * 16 + q4 * 4);
                #pragma unroll
                for (int r = 0; r < 4; ++r) {
                    const int n = ni * 16 + q4 * 4 + r;
                    float s = 0.f;
                    if (n < N_)
                        s = __builtin_exp2f(sacc[ni][r] * SC + (float)bv[r]);
                    sacc[ni][r] = s;
                    den += s;
                }
            }
            den += __shfl_xor(den, 16);
            den += __shfl_xor(den, 32);
            const float ri = __builtin_amdgcn_rcpf(den);

            // P write (exact zeros for n>=49; rows m>=49 skipped -> stale,
            // masked at ao staging)
            if (m < N_) {
                #pragma unroll
                for (int ni = 0; ni < 4; ++ni) {
                    bf16x4 o;
                    #pragma unroll
                    for (int r = 0; r < 4; ++r) o[r] = (bf16_t)(sacc[ni][r] * ri);
                    *(bf16x4*)(pb + l15 * P_STRIDE + ni * 16 + q4 * 4) = o;
                }
            }

            f32x4 o0 = z4, o1 = z4;
            #pragma unroll
            for (int ks2 = 0; ks2 < 2; ++ks2) {
                bf16x8 pf = *(const bf16x8*)(pb + l15 * P_STRIDE + ks2 * 32 + q4 * 8);
                o0 = __builtin_amdgcn_mfma_f32_16x16x32_bf16(pf, vf[ks2][0], o0, 0, 0, 0);
                o1 = __builtin_amdgcn_mfma_f32_16x16x32_bf16(pf, vf[ks2][1], o1, 0, 0, 0);
            }
            #pragma unroll
            for (int r = 0; r < 4; ++r) {
                const int ms = mt * 16 + q4 * 4 + r;
                if (ms < N_) {
                    aq[ms * AO_STRIDE + l15]      = (bf16_t)o0[r];
                    aq[ms * AO_STRIDE + 16 + l15] = (bf16_t)o1[r];
                }
            }
        }
    }
    __syncthreads();   // B1: all heads' ao staged in arenas

    // ---------------- P4: out = ao @ Wproj + b, 2 col-tiles/wave ----------
    {
        f32x4 pacc[2][4];
        #pragma unroll
        for (int jj = 0; jj < 2; ++jj)
            #pragma unroll
            for (int mi = 0; mi < 4; ++mi) pacc[jj][mi] = z4;

        bf16x8 wfc[2], afc[4];
        #pragma unroll
        for (int jj = 0; jj < 2; ++jj)
            wfc[jj] = *(const bf16x8*)(wprojT +
                ((size_t)((wave * 2 + jj) * 12 + 0) * 64 + lane) * 8);
        #pragma unroll
        for (int mi = 0; mi < 4; ++mi)
            afc[mi] = *(const bf16x8*)((bf16_t*)(smem + ARENA_OFF)
                                       + XF_ROW(mi) * AO_STRIDE + q4 * 8);

        #pragma unroll
        for (int ks = 0; ks < 12; ++ks) {
            bf16x8 wfn[2], afn[4];
            if (ks < 11) {
                #pragma unroll
                for (int jj = 0; jj < 2; ++jj)
                    wfn[jj] = *(const bf16x8*)(wprojT +
                        ((size_t)((wave * 2 + jj) * 12 + ks + 1) * 64 + lane) * 8);
                bf16_t* an = (bf16_t*)(smem + ARENA_OFF + (ks + 1) * ARENA_SZ);
                #pragma unroll
                for (int mi = 0; mi < 4; ++mi)
                    afn[mi] = *(const bf16x8*)(an + XF_ROW(mi) * AO_STRIDE + q4 * 8);
            }
            #pragma unroll
            for (int jj = 0; jj < 2; ++jj)
                #pragma unroll
                for (int mi = 0; mi < 4; ++mi)
                    pacc[jj][mi] = __builtin_amdgcn_mfma_f32_16x16x32_bf16(
                        afc[mi], wfc[jj], pacc[jj][mi], 0, 0, 0);
            if (ks < 11) {
                #pragma unroll
                for (int jj = 0; jj < 2; ++jj) wfc[jj] = wfn[jj];
                #pragma unroll
                for (int mi = 0; mi < 4; ++mi) afc[mi] = afn[mi];
            }
        }
        float* og = out + (size_t)b * (N_ * C_);
        #pragma unroll
        for (int jj = 0; jj < 2; ++jj) {
            const int n = (wave * 2 + jj) * 16 + l15;
            const float bias = proj_b[n];
            #pragma unroll
            for (int mi = 0; mi < 4; ++mi) {
                #pragma unroll
                for (int r = 0; r < 4; ++r) {
                    const int m = mi * 16 + q4 * 4 + r;
                    if (m < N_) og[m * C_ + n] = pacc[jj][mi][r] + bias;
                }
            }
        }
    }
}

// ---------------------------------------------------------------------------
extern "C" void kernel_launch(void* const* d_in, const int* in_sizes, int n_in,
                              void* d_out, int out_size, void* d_ws, size_t ws_size,
                              hipStream_t stream)
{
    const float* x      = (const float*)d_in[0];
    const float* mask   = (const float*)d_in[1];
    const float* qkv_w  = (const float*)d_in[2];
    const float* qkv_b  = (const float*)d_in[3];
    const float* proj_w = (const float*)d_in[4];
    const float* proj_b = (const float*)d_in[5];
    const float* rpb    = (const float*)d_in[6];
    float* out = (float*)d_out;

    bf16_t* wqkvT  = (bf16_t*)d_ws;
    bf16_t* wprojT = wqkvT + WQKV_ELEMS;
    bf16_t* btbl   = wprojT + WPROJ_ELEMS;   // 64*12*49*64 bf16 = 4.8 MB

    prep_all<<<288 + NW_ * H_, 256, 0, stream>>>(qkv_w, proj_w, mask, rpb,
                                                 wqkvT, wprojT, btbl);
    fused_window_attn<<<2048, 768, 0, stream>>>(x, qkv_b, proj_b,
                                                wqkvT, wprojT, btbl, out);
}